// Round 12
// baseline (36.333 us; speedup 1.0000x reference)
//
#include <hip/hip_runtime.h>
#include <hip/hip_bf16.h>

#define B_   32
#define N_   128
#define AH_  512
#define AW_  512
#define LCAP 64    // per-chunk list capacity (one 64-box ballot chunk)

// compiler-only reordering fence; one wave's DS ops execute in issue order
#define CFENCE() asm volatile("" ::: "memory")

typedef __fp16 h2_t __attribute__((ext_vector_type(2)));   // matches cvt_pkrtz
union f_h2 { float f; h2_t h; };

// ---------------------------------------------------------------------------
// R12 = R11 with the cvt_pkrtz return-type fixed (__fp16 vec2, not _Float16).
// R11's theory unchanged: R6 skeleton with the raster loop slimmed per the
// issue model (R6 issue ~= 1600cy/pair, ~50% of time, raster ~65% of issue):
//  - mask is INTERLEAVED [x][2] (rows adjacent): ab==3 boxes (~97%) write one
//    ds_write_b64 per chunk-iter (was 2x b32 + 2 uniform branch tests)
//  - box record packs to ONE float4 {pk, f16x2(x1m,x2m), rv0, rv1}: one
//    ds_read_b128 prefetch + one ds_write_b128 compaction per box (was 2+2)
//  - bbox loads issued BEFORE att loads: geometry's vmcnt wait no longer
//    drains the att HBM loads (they land during raster)
// Everything else is R6 verbatim: 2 independent waves/block, no barriers,
// 2 consecutive rows/wave, ballot compaction in index order, gated logs,
// wave-sum -> ws, fused 1-block tail.
// ---------------------------------------------------------------------------
__global__ __launch_bounds__(128) void row_bce_kernel(
    const float* __restrict__ att,
    const float* __restrict__ bboxs,
    const int*   __restrict__ img_h_p,
    const int*   __restrict__ img_w_p,
    float*       __restrict__ wave_sums)
{
    const int t    = threadIdx.x;
    const int lane = t & 63;
    const int wid  = t >> 6;                    // 0..1
    const int task = (blockIdx.x << 1) | wid;   // 0..8191
    const int b    = task >> 8;                 // 256 tasks per image
    const int y0   = (task & 255) << 1;         // rows y0, y0+1

    __shared__ float4 s_geo[2][LCAP];           // {pk, f16x2(x1m,x2m), rv0, rv1}
    __shared__ float  s_mask[2][AW_][2];        // [wid][x][row]  (interleaved)

    // ---- bbox loads FIRST (geometry waits only on these) ----
    float4 c4[2];
    float  lab[2];
    #pragma unroll
    for (int k = 0; k < 2; ++k) {
        const float* bp = bboxs + ((size_t)b * N_ + lane + 64 * k) * 5;
        c4[k]  = *(const float4*)bp;
        lab[k] = bp[4];
    }

    // ---- att loads: px = h*128 + 2*lane + {0,1}, rows y0 / y0+1 ----
    const float* a0 = att + ((size_t)b * AH_ + y0) * AW_;
    float2 P0[4], P1[4];
    #pragma unroll
    for (int h = 0; h < 4; ++h) {
        P0[h] = *(const float2*)(a0 + h * 128 + 2 * lane);
        P1[h] = *(const float2*)(a0 + AW_ + h * 128 + 2 * lane);
    }

    const float fw  = (float)(*img_w_p);
    const float fh  = (float)(*img_h_p);
    const float sxs = (float)AW_ / fw;
    const float sys = (float)AH_ / fh;

    // ---- box geometry, once per wave (boxes lane and lane+64) ----
    bool   act_any[2];
    float4 rec[2];
    #pragma unroll
    for (int k = 0; k < 2; ++k) {
        const float c0 = c4[k].x, c1 = c4[k].y, c2 = c4[k].z, c3 = c4[k].w;
        const bool valid = (lab[k] != -1.0f) && (c0 <= fw) && (c1 <= fh)
                                             && (c2 <= fw) && (c3 <= fh);
        const float bx1 = c0 * sxs, by1 = c1 * sys;
        const float bx2 = c2 * sxs, by2 = c3 * sys;
        const float fx1 = floorf(bx1), fy1 = floorf(by1);
        const float x1m = fx1 + 1.0f - bx1;
        const float y1m = fy1 + 1.0f - by1;
        const float x2m = bx2 - floorf(bx2);
        const float y2m = by2 - floorf(by2);
        const int x1 = (int)fmaxf(fx1, 0.0f);
        const int y1 = (int)fmaxf(fy1, 0.0f);
        const int x2 = (int)fminf(ceilf(bx2) + 1.0f, (float)AW_);
        const int y2 = (int)fminf(ceilf(by2) + 1.0f, (float)AH_);

        int   ab = 0;
        float rv0 = 1.0f, rv1 = 1.0f;
        #pragma unroll
        for (int r = 0; r < 2; ++r) {
            const int y = y0 + r;
            const bool a = valid && (y >= y1) && (y < y2);
            ab |= a ? (1 << r) : 0;
            const float rw = ((y == y1)     ? y1m : 1.0f)
                           * ((y == y2 - 1) ? y2m : 1.0f);
            if (r == 0) rv0 = rw; else rv1 = rw;
        }
        act_any[k] = (ab != 0);

        f_h2 u;
        u.h = __builtin_amdgcn_cvt_pkrtz(x1m, x2m);   // pack edges to f16x2
        rec[k] = make_float4(
            __int_as_float((unsigned)x1 | ((unsigned)x2 << 10) | ((unsigned)ab << 20)),
            u.f, rv0, rv1);
    }

    const unsigned long long ltm  = (1ull << lane) - 1ull;
    const unsigned long long bal0 = __ballot(act_any[0]);
    const unsigned long long bal1 = __ballot(act_any[1]);
    const bool have = (bal0 | bal1) != 0ull;

    float*  mbase = &s_mask[wid][0][0];
    float4* m4    = (float4*)mbase;

    if (have) {
        // zero the wave's 4KB interleaved mask: 4x ds_write_b128
        const float4 z = make_float4(0.f, 0.f, 0.f, 0.f);
        #pragma unroll
        for (int q = 0; q < 4; ++q) m4[lane + 64 * q] = z;
        CFENCE();

        // ---- two 64-box chunks in index order; list buffer reused ----
        #pragma unroll
        for (int k = 0; k < 2; ++k) {
            const unsigned long long bal = (k == 0) ? bal0 : bal1;
            const int cnt = __popcll(bal);
            if (cnt == 0) continue;
            if (act_any[k]) {
                const int slot = __popcll(bal & ltm);
                s_geo[wid][slot] = rec[k];      // one ds_write_b128
            }
            CFENCE();   // compaction writes precede list reads (in-order DS)

            float4 gc = s_geo[wid][0];          // one ds_read_b128 per box
            for (int i = 0; i < cnt; ++i) {
                const float4 g = gc;
                if (i + 1 < cnt) gc = s_geo[wid][i + 1];   // 1-deep prefetch

                const unsigned pks =
                    (unsigned)__builtin_amdgcn_readfirstlane(__float_as_int(g.x));
                const int e1 = (int)(pks & 1023u);
                const int e2 = (int)((pks >> 10) & 1023u);
                const int ab = (int)(pks >> 20);
                f_h2 u; u.f = g.y;
                const float x1m = (float)u.h.x;
                const float x2m = (float)u.h.y;

                if (ab == 3) {                  // fast path: one b64 write/iter
                    for (int x = e1 + lane; x < e2; x += 64) {
                        const float edge = ((x == e1)     ? x1m : 1.0f)
                                         * ((x == e2 - 1) ? x2m : 1.0f);
                        *(float2*)(mbase + x * 2) = make_float2(g.z * edge,
                                                                g.w * edge);
                    }
                } else {                        // single-row box (boundary)
                    const int   r  = ab >> 1;   // ab==1 -> row0, ab==2 -> row1
                    const float rv = r ? g.w : g.z;
                    for (int x = e1 + lane; x < e2; x += 64) {
                        const float edge = ((x == e1)     ? x1m : 1.0f)
                                         * ((x == e2 - 1) ? x2m : 1.0f);
                        mbase[x * 2 + r] = rv * edge;
                    }
                }
            }
            CFENCE();   // raster reads precede next chunk's compaction writes
        }
    }

    // ---- BCE: lane j owns px {h*128+2j, +1}; one b128 mask read covers
    //      both pixels x both rows. p in [1e-4,1-1e-4]: no clamps. ----
    float acc = 0.0f;
    #pragma unroll
    for (int h = 0; h < 4; ++h) {
        float4 m = make_float4(0.f, 0.f, 0.f, 0.f);
        if (have) m = m4[h * 64 + lane];
        const float2 p0 = P0[h];                // row0: px A, B
        const float2 p1 = P1[h];                // row1: px A, B
        const bool nz = (m.x != 0.f) | (m.y != 0.f)
                      | (m.z != 0.f) | (m.w != 0.f);
        if (__any(nz)) {
            const float l0A = __logf(1.0f - p0.x), g0A = __logf(p0.x);
            const float l1A = __logf(1.0f - p1.x), g1A = __logf(p1.x);
            const float l0B = __logf(1.0f - p0.y), g0B = __logf(p0.y);
            const float l1B = __logf(1.0f - p1.y), g1B = __logf(p1.y);
            acc += l0A + m.x * (g0A - l0A);     // px A row0
            acc += l1A + m.y * (g1A - l1A);     // px A row1
            acc += l0B + m.z * (g0B - l0B);     // px B row0
            acc += l1B + m.w * (g1B - l1B);     // px B row1
        } else {
            acc += __logf(1.0f - p0.x) + __logf(1.0f - p0.y)
                 + __logf(1.0f - p1.x) + __logf(1.0f - p1.y);
        }
    }

    // ---- wave reduction -> per-task partial ----
    #pragma unroll
    for (int off = 32; off; off >>= 1) acc += __shfl_down(acc, off, 64);
    if (lane == 0) wave_sums[task] = acc;
}

// ---------------------------------------------------------------------------
// Fused tail: per-image reduce of 256 task partials + any_valid gate +
// batch mean. One block, 1024 threads (32 workers per image).
// ---------------------------------------------------------------------------
__global__ __launch_bounds__(1024) void final_kernel(
    const float* __restrict__ bboxs,
    const int*   __restrict__ img_h_p,
    const int*   __restrict__ img_w_p,
    const float* __restrict__ wave_sums,
    float*       __restrict__ out)
{
    const int t = threadIdx.x;
    const int b = t >> 5;        // image 0..31
    const int j = t & 31;        // worker within image

    __shared__ float s_sum[1024];
    __shared__ int   s_any[1024];
    __shared__ float s_loss[B_];

    float s = 0.0f;
    #pragma unroll
    for (int k = 0; k < 8; ++k) s += wave_sums[b * 256 + j + 32 * k];
    s_sum[t] = s;

    const float fw = (float)(*img_w_p);
    const float fh = (float)(*img_h_p);
    int av = 0;
    const float* bp = bboxs + (size_t)b * N_ * 5;
    #pragma unroll
    for (int n = j * 4; n < j * 4 + 4; ++n) {
        const float c0 = bp[n * 5 + 0];
        const float c1 = bp[n * 5 + 1];
        const float c2 = bp[n * 5 + 2];
        const float c3 = bp[n * 5 + 3];
        const float lab = bp[n * 5 + 4];
        av |= ((lab != -1.0f) && (c0 <= fw) && (c1 <= fh)
                              && (c2 <= fw) && (c3 <= fh)) ? 1 : 0;
    }
    s_any[t] = av;
    __syncthreads();

    if (j == 0) {
        float sum = 0.0f;
        int anyv = 0;
        for (int k = 0; k < 32; ++k) {
            sum  += s_sum[b * 32 + k];
            anyv |= s_any[b * 32 + k];
        }
        s_loss[b] = anyv ? (-sum * (1.0f / (float)(AH_ * AW_))) : 0.0f;
    }
    __syncthreads();

    if (t == 0) {
        float total = 0.0f;
        for (int k = 0; k < B_; ++k) total += s_loss[k];
        out[0] = total * (1.0f / (float)B_);
    }
}

extern "C" void kernel_launch(void* const* d_in, const int* in_sizes, int n_in,
                              void* d_out, int out_size, void* d_ws, size_t ws_size,
                              hipStream_t stream)
{
    const float* att   = (const float*)d_in[0];   // (32,1,512,512) f32
    const float* bboxs = (const float*)d_in[1];   // (32,128,5) f32
    const int*   img_h = (const int*)d_in[2];     // scalar
    const int*   img_w = (const int*)d_in[3];     // scalar
    float* out = (float*)d_out;
    float* wave_sums = (float*)d_ws;              // 8192 floats (32 KB)

    row_bce_kernel<<<B_ * AH_ / 4, 128, 0, stream>>>(att, bboxs, img_h, img_w, wave_sums);
    final_kernel<<<1, 1024, 0, stream>>>(bboxs, img_h, img_w, wave_sums, out);
}